// Round 1
// baseline (736.079 us; speedup 1.0000x reference)
//
#include <hip/hip_runtime.h>
#include <math.h>

#define EMB 128
#define HIDN 256

// ---------------- CSR build ----------------

__global__ void zero_i32(int* p, int n) {
    int i = blockIdx.x * blockDim.x + threadIdx.x;
    if (i < n) p[i] = 0;
}

__global__ void hist_kernel(const int* __restrict__ dst, int E, int* __restrict__ cnt) {
    int i = blockIdx.x * blockDim.x + threadIdx.x;
    if (i < E) atomicAdd(&cnt[dst[i]], 1);
}

// Single-block exclusive scan over cnt[0..Nn). cntcur is counts on input,
// cursor (== exclusive prefix) on output. off gets exclusive prefix + off[Nn]=E.
__global__ void scan_kernel(int* __restrict__ cntcur, int* __restrict__ off, int Nn, int E) {
    __shared__ int sums[1024];
    const int t = threadIdx.x;
    const int T = blockDim.x;
    const int chunk = (Nn + T - 1) / T;
    const int lo = t * chunk;
    const int hi = min(lo + chunk, Nn);
    int s = 0;
    for (int i = lo; i < hi; ++i) s += cntcur[i];
    sums[t] = s;
    __syncthreads();
    // Hillis-Steele inclusive scan
    for (int d = 1; d < T; d <<= 1) {
        int v = (t >= d) ? sums[t - d] : 0;
        __syncthreads();
        sums[t] += v;
        __syncthreads();
    }
    int run = (t == 0) ? 0 : sums[t - 1];
    for (int i = lo; i < hi; ++i) {
        int c = cntcur[i];       // read before aliasing write
        off[i] = run;
        cntcur[i] = run;         // cursor for scatter
        run += c;
    }
    if (t == 0) off[Nn] = E;
}

__global__ void scatter_kernel(const int* __restrict__ src, const int* __restrict__ dst,
                               int E, int* __restrict__ cur, int* __restrict__ sorted) {
    int i = blockIdx.x * blockDim.x + threadIdx.x;
    if (i < E) {
        int d = dst[i];
        int p = atomicAdd(&cur[d], 1);
        sorted[p] = src[i];
    }
}

// ---------------- fused segment-max + self-add ----------------
// xs[v] = x[v] + (deg(v)>0 ? max_{e: dst=v} x[src[e]] : 0)
// One wave per node; lane holds VEC contiguous features. D = 64*VEC.

template <int VEC>
__global__ void segmax_add(const float* __restrict__ x, const int* __restrict__ off,
                           const int* __restrict__ sorted, float* __restrict__ xs, int Nn) {
    const int D = VEC * 64;
    const int node = blockIdx.x * (blockDim.x >> 6) + (threadIdx.x >> 6);
    const int lane = threadIdx.x & 63;
    if (node >= Nn) return;
    const int beg = off[node];
    const int end = off[node + 1];
    const int col = lane * VEC;

    float acc[VEC];
#pragma unroll
    for (int i = 0; i < VEC; ++i) acc[i] = -INFINITY;

    for (int e = beg; e < end; ++e) {
        int s = sorted[e];
        const float* row = x + (size_t)s * D + col;
        if (VEC == 4) {
            float4 v = *reinterpret_cast<const float4*>(row);
            acc[0] = fmaxf(acc[0], v.x);
            acc[1] = fmaxf(acc[1], v.y);
            acc[2] = fmaxf(acc[2], v.z);
            acc[3] = fmaxf(acc[3], v.w);
        } else {
            float2 v = *reinterpret_cast<const float2*>(row);
            acc[0] = fmaxf(acc[0], v.x);
            acc[1] = fmaxf(acc[1], v.y);
        }
    }

    const bool hasEdges = (end > beg);
    const float* xr = x + (size_t)node * D + col;
    float* outp = xs + (size_t)node * D + col;
    if (VEC == 4) {
        float4 xv = *reinterpret_cast<const float4*>(xr);
        float4 o;
        o.x = xv.x + (hasEdges ? acc[0] : 0.0f);
        o.y = xv.y + (hasEdges ? acc[1] : 0.0f);
        o.z = xv.z + (hasEdges ? acc[2] : 0.0f);
        o.w = xv.w + (hasEdges ? acc[3] : 0.0f);
        *reinterpret_cast<float4*>(outp) = o;
    } else {
        float2 xv = *reinterpret_cast<const float2*>(xr);
        float2 o;
        o.x = xv.x + (hasEdges ? acc[0] : 0.0f);
        o.y = xv.y + (hasEdges ? acc[1] : 0.0f);
        *reinterpret_cast<float2*>(outp) = o;
    }
}

// ---------------- fp32 GEMM: C = A[M,K] @ W[K,N] + bias, optional ReLU ----------------
// BM=64, BN=64, BK=32. Block 256 threads (16x16), 4x4 micro-tile.

__global__ __launch_bounds__(256) void gemm_bias_act(
    const float* __restrict__ A, const float* __restrict__ W,
    const float* __restrict__ bias, float* __restrict__ C,
    int M, int K, int N, int relu)
{
    __shared__ float sA[32 * 68];  // [k][m], stride 68 keeps float4 reads 16B-aligned
    __shared__ float sB[32 * 68];  // [k][n]

    const int tid = threadIdx.x;
    const int tx = tid & 15;   // col group
    const int ty = tid >> 4;   // row group
    const int r0 = blockIdx.x * 64;
    const int n0 = blockIdx.y * 64;

    float acc[4][4] = {{0.f}};

    const int am = tid >> 3;          // 0..31 (row within half-tile)
    const int ak = (tid & 7) * 4;     // 0..28 (k offset)
    const int bk = tid >> 4;          // 0..15 (k row within half)
    const int bn = (tid & 15) * 4;    // 0..60

    for (int k0 = 0; k0 < K; k0 += 32) {
        // stage A (transposed) : sA[k][m] = A[r0+m][k0+k]
#pragma unroll
        for (int h = 0; h < 2; ++h) {
            int m = am + 32 * h;
            int row = r0 + m;
            row = row < M ? row : (M - 1);
            float4 a = *reinterpret_cast<const float4*>(A + (size_t)row * K + k0 + ak);
            sA[(ak + 0) * 68 + m] = a.x;
            sA[(ak + 1) * 68 + m] = a.y;
            sA[(ak + 2) * 68 + m] = a.z;
            sA[(ak + 3) * 68 + m] = a.w;
        }
        // stage B : sB[k][n] = W[k0+k][n0+n]
#pragma unroll
        for (int h = 0; h < 2; ++h) {
            int k = bk + 16 * h;
            float4 b = *reinterpret_cast<const float4*>(W + (size_t)(k0 + k) * N + n0 + bn);
            *reinterpret_cast<float4*>(&sB[k * 68 + bn]) = b;
        }
        __syncthreads();

#pragma unroll
        for (int k = 0; k < 32; ++k) {
            float4 a = *reinterpret_cast<const float4*>(&sA[k * 68 + 4 * ty]);
            float4 b = *reinterpret_cast<const float4*>(&sB[k * 68 + 4 * tx]);
            acc[0][0] += a.x * b.x; acc[0][1] += a.x * b.y; acc[0][2] += a.x * b.z; acc[0][3] += a.x * b.w;
            acc[1][0] += a.y * b.x; acc[1][1] += a.y * b.y; acc[1][2] += a.y * b.z; acc[1][3] += a.y * b.w;
            acc[2][0] += a.z * b.x; acc[2][1] += a.z * b.y; acc[2][2] += a.z * b.z; acc[2][3] += a.z * b.w;
            acc[3][0] += a.w * b.x; acc[3][1] += a.w * b.y; acc[3][2] += a.w * b.z; acc[3][3] += a.w * b.w;
        }
        __syncthreads();
    }

    float4 bv = *reinterpret_cast<const float4*>(bias + n0 + 4 * tx);
#pragma unroll
    for (int i = 0; i < 4; ++i) {
        int row = r0 + 4 * ty + i;
        if (row < M) {
            float4 o;
            o.x = acc[i][0] + bv.x;
            o.y = acc[i][1] + bv.y;
            o.z = acc[i][2] + bv.z;
            o.w = acc[i][3] + bv.w;
            if (relu) {
                o.x = fmaxf(o.x, 0.f); o.y = fmaxf(o.y, 0.f);
                o.z = fmaxf(o.z, 0.f); o.w = fmaxf(o.w, 0.f);
            }
            *reinterpret_cast<float4*>(C + (size_t)row * N + n0 + 4 * tx) = o;
        }
    }
}

// ---------------- launch ----------------

extern "C" void kernel_launch(void* const* d_in, const int* in_sizes, int n_in,
                              void* d_out, int out_size, void* d_ws, size_t ws_size,
                              hipStream_t stream) {
    const int*   src = (const int*)d_in[0];
    const int*   dst = (const int*)d_in[1];
    const float* emb = (const float*)d_in[2];
    const float* W1  = (const float*)d_in[3];
    const float* b1  = (const float*)d_in[4];
    const float* W2  = (const float*)d_in[5];
    const float* b2  = (const float*)d_in[6];
    const float* W3  = (const float*)d_in[7];
    const float* b3  = (const float*)d_in[8];
    float* out = (float*)d_out;

    const int E  = in_sizes[0];
    const int Nn = in_sizes[2] / EMB;

    char* ws = (char*)d_ws;
    auto align256 = [](size_t x) { return (x + 255) & ~(size_t)255; };
    size_t p = 0;
    int* off    = (int*)(ws + p); p = align256(p + (size_t)(Nn + 1) * 4);
    int* cur    = (int*)(ws + p); p = align256(p + (size_t)(Nn + 1) * 4);
    int* sorted = (int*)(ws + p); p = align256(p + (size_t)E * 4);
    float* bufA = (float*)(ws + p); p = align256(p + (size_t)Nn * HIDN * 4);
    float* bufB = (float*)(ws + p); p = align256(p + (size_t)Nn * HIDN * 4);

    // ---- CSR build (by dst) ----
    zero_i32<<<(Nn + 255) / 256, 256, 0, stream>>>(cur, Nn);
    hist_kernel<<<(E + 255) / 256, 256, 0, stream>>>(dst, E, cur);
    scan_kernel<<<1, 1024, 0, stream>>>(cur, off, Nn, E);
    scatter_kernel<<<(E + 255) / 256, 256, 0, stream>>>(src, dst, E, cur, sorted);

    const int segBlocks = (Nn + 3) / 4;

    // ---- Layer 1: D=128 -> 256, relu ----
    segmax_add<2><<<segBlocks, 256, 0, stream>>>(emb, off, sorted, bufB, Nn);
    {
        dim3 grid((Nn + 63) / 64, 256 / 64);
        gemm_bias_act<<<grid, 256, 0, stream>>>(bufB, W1, b1, bufA, Nn, 128, 256, 1);
    }

    // ---- Layer 2: D=256 -> 256, relu ----
    segmax_add<4><<<segBlocks, 256, 0, stream>>>(bufA, off, sorted, bufB, Nn);
    {
        dim3 grid((Nn + 63) / 64, 256 / 64);
        gemm_bias_act<<<grid, 256, 0, stream>>>(bufB, W2, b2, bufA, Nn, 256, 256, 1);
    }

    // ---- Layer 3: D=256 -> 128, no relu ----
    segmax_add<4><<<segBlocks, 256, 0, stream>>>(bufA, off, sorted, bufB, Nn);
    {
        dim3 grid((Nn + 63) / 64, 128 / 64);
        gemm_bias_act<<<grid, 256, 0, stream>>>(bufB, W3, b3, out, Nn, 256, 128, 0);
    }
}

// Round 2
// 562.606 us; speedup vs baseline: 1.3083x; 1.3083x over previous
//
#include <hip/hip_runtime.h>
#include <math.h>

#define EMB 128
#define HIDN 256

typedef _Float16 half8 __attribute__((ext_vector_type(8)));
typedef _Float16 half4 __attribute__((ext_vector_type(4)));
typedef _Float16 half2v __attribute__((ext_vector_type(2)));
typedef float f32x4 __attribute__((ext_vector_type(4)));

// ---------------- CSR build ----------------

__global__ void zero_i32(int* p, int n) {
    int i = blockIdx.x * blockDim.x + threadIdx.x;
    if (i < n) p[i] = 0;
}

__global__ void hist_kernel(const int* __restrict__ dst, int E, int* __restrict__ cnt) {
    int i = blockIdx.x * blockDim.x + threadIdx.x;
    if (i < E) atomicAdd(&cnt[dst[i]], 1);
}

__global__ void scan_kernel(int* __restrict__ cntcur, int* __restrict__ off, int Nn, int E) {
    __shared__ int sums[1024];
    const int t = threadIdx.x;
    const int T = blockDim.x;
    const int chunk = (Nn + T - 1) / T;
    const int lo = t * chunk;
    const int hi = min(lo + chunk, Nn);
    int s = 0;
    for (int i = lo; i < hi; ++i) s += cntcur[i];
    sums[t] = s;
    __syncthreads();
    for (int d = 1; d < T; d <<= 1) {
        int v = (t >= d) ? sums[t - d] : 0;
        __syncthreads();
        sums[t] += v;
        __syncthreads();
    }
    int run = (t == 0) ? 0 : sums[t - 1];
    for (int i = lo; i < hi; ++i) {
        int c = cntcur[i];
        off[i] = run;
        cntcur[i] = run;
        run += c;
    }
    if (t == 0) off[Nn] = E;
}

__global__ void scatter_kernel(const int* __restrict__ src, const int* __restrict__ dst,
                               int E, int* __restrict__ cur, int* __restrict__ sorted) {
    int i = blockIdx.x * blockDim.x + threadIdx.x;
    if (i < E) {
        int d = dst[i];
        int p = atomicAdd(&cur[d], 1);
        sorted[p] = src[i];
    }
}

// ---------------- dtype conversion helpers ----------------

__global__ void f32_to_f16(const float* __restrict__ in, _Float16* __restrict__ out, int n4) {
    int i = blockIdx.x * blockDim.x + threadIdx.x;
    if (i < n4) {
        float4 v = *reinterpret_cast<const float4*>(in + (size_t)i * 4);
        half4 h;
        h[0] = (_Float16)v.x; h[1] = (_Float16)v.y;
        h[2] = (_Float16)v.z; h[3] = (_Float16)v.w;
        *reinterpret_cast<half4*>(out + (size_t)i * 4) = h;
    }
}

// Wt[n*K + k] = (f16) W[k*N + n]
__global__ void transpose_f16(const float* __restrict__ W, _Float16* __restrict__ Wt, int K, int N) {
    int i = blockIdx.x * blockDim.x + threadIdx.x;
    if (i < K * N) {
        int k = i / N;
        int n = i - k * N;
        Wt[(size_t)n * K + k] = (_Float16)W[i];
    }
}

// ---------------- fused segment-max + self-add (fp16) ----------------
// xs[v] = x[v] + (deg(v)>0 ? max_{e: dst=v} x[src[e]] : 0); D = 64*VEC halves.

template <int VEC>
__global__ void segmax_add_h(const _Float16* __restrict__ x, const int* __restrict__ off,
                             const int* __restrict__ sorted, _Float16* __restrict__ xs, int Nn) {
    const int D = VEC * 64;
    const int node = blockIdx.x * (blockDim.x >> 6) + (threadIdx.x >> 6);
    const int lane = threadIdx.x & 63;
    if (node >= Nn) return;
    const int beg = off[node];
    const int end = off[node + 1];
    const int col = lane * VEC;

    float acc[VEC];
#pragma unroll
    for (int i = 0; i < VEC; ++i) acc[i] = -INFINITY;

    for (int e = beg; e < end; ++e) {
        int s = sorted[e];
        const _Float16* row = x + (size_t)s * D + col;
        if (VEC == 4) {
            half4 v = *reinterpret_cast<const half4*>(row);
#pragma unroll
            for (int i = 0; i < 4; ++i) acc[i] = fmaxf(acc[i], (float)v[i]);
        } else {
            half2v v = *reinterpret_cast<const half2v*>(row);
#pragma unroll
            for (int i = 0; i < 2; ++i) acc[i] = fmaxf(acc[i], (float)v[i]);
        }
    }

    const bool hasEdges = (end > beg);
    const _Float16* xr = x + (size_t)node * D + col;
    _Float16* outp = xs + (size_t)node * D + col;
    if (VEC == 4) {
        half4 xv = *reinterpret_cast<const half4*>(xr);
        half4 o;
#pragma unroll
        for (int i = 0; i < 4; ++i)
            o[i] = (_Float16)((float)xv[i] + (hasEdges ? acc[i] : 0.0f));
        *reinterpret_cast<half4*>(outp) = o;
    } else {
        half2v xv = *reinterpret_cast<const half2v*>(xr);
        half2v o;
#pragma unroll
        for (int i = 0; i < 2; ++i)
            o[i] = (_Float16)((float)xv[i] + (hasEdges ? acc[i] : 0.0f));
        *reinterpret_cast<half2v*>(outp) = o;
    }
}

// ---------------- MFMA fp16 GEMM ----------------
// C[M,N] = A[M,K] @ W[K,N] + bias (+ReLU). A fp16 row-major, Wt fp16 [N][K].
// BM=128, BN=128, BK=32. 256 threads = 4 waves (2x2), each wave 64x64 out.
// LDS layout: s[4][128][8] halves -> k-subtile j holds cols k0+8j..k0+8j+7.
// OUT_F32: write float to C (final layer), else fp16.

template <int OUT_F32, int RELU>
__global__ __launch_bounds__(256) void gemm_h(
    const _Float16* __restrict__ A, const _Float16* __restrict__ Wt,
    const float* __restrict__ bias, void* __restrict__ C,
    int M, int K, int N)
{
    __shared__ _Float16 sA[4 * 128 * 8];
    __shared__ _Float16 sB[4 * 128 * 8];

    const int tid = threadIdx.x;
    const int r0 = blockIdx.x * 128;
    const int n0 = blockIdx.y * 128;

    const int wave = tid >> 6;
    const int lane = tid & 63;
    const int g = lane >> 4;        // k-subtile group
    const int r = lane & 15;        // row (A) / col (B) within 16
    const int m_base = (wave >> 1) * 64;
    const int n_base = (wave & 1) * 64;

    f32x4 acc[4][4];
#pragma unroll
    for (int i = 0; i < 4; ++i)
#pragma unroll
        for (int j = 0; j < 4; ++j) acc[i][j] = (f32x4){0.f, 0.f, 0.f, 0.f};

    for (int k0 = 0; k0 < K; k0 += 32) {
        // stage: 512 slots each side, 256 threads -> 2 slots/thread/side
#pragma unroll
        for (int h = 0; h < 2; ++h) {
            int s = tid + h * 256;
            int row = s >> 2;
            int j = s & 3;
            int ar = r0 + row; ar = ar < M ? ar : (M - 1);
            half8 av = *reinterpret_cast<const half8*>(A + (size_t)ar * K + k0 + j * 8);
            *reinterpret_cast<half8*>(&sA[((j << 7) + row) << 3]) = av;
            half8 bv = *reinterpret_cast<const half8*>(Wt + (size_t)(n0 + row) * K + k0 + j * 8);
            *reinterpret_cast<half8*>(&sB[((j << 7) + row) << 3]) = bv;
        }
        __syncthreads();

        half8 aF[4], bF[4];
#pragma unroll
        for (int mi = 0; mi < 4; ++mi)
            aF[mi] = *reinterpret_cast<half8*>(&sA[((g << 7) + m_base + mi * 16 + r) << 3]);
#pragma unroll
        for (int ni = 0; ni < 4; ++ni)
            bF[ni] = *reinterpret_cast<half8*>(&sB[((g << 7) + n_base + ni * 16 + r) << 3]);

#pragma unroll
        for (int mi = 0; mi < 4; ++mi)
#pragma unroll
            for (int ni = 0; ni < 4; ++ni)
                acc[mi][ni] = __builtin_amdgcn_mfma_f32_16x16x32_f16(aF[mi], bF[ni], acc[mi][ni], 0, 0, 0);

        __syncthreads();
    }

    // epilogue: C/D layout col = lane&15, row = (lane>>4)*4 + q
#pragma unroll
    for (int ni = 0; ni < 4; ++ni) {
        int col = n0 + n_base + ni * 16 + r;
        float bv = bias[col];
#pragma unroll
        for (int mi = 0; mi < 4; ++mi) {
#pragma unroll
            for (int q = 0; q < 4; ++q) {
                int row = r0 + m_base + mi * 16 + g * 4 + q;
                if (row < M) {
                    float v = acc[mi][ni][q] + bv;
                    if (RELU) v = fmaxf(v, 0.f);
                    if (OUT_F32)
                        ((float*)C)[(size_t)row * N + col] = v;
                    else
                        ((_Float16*)C)[(size_t)row * N + col] = (_Float16)v;
                }
            }
        }
    }
}

// ---------------- launch ----------------

extern "C" void kernel_launch(void* const* d_in, const int* in_sizes, int n_in,
                              void* d_out, int out_size, void* d_ws, size_t ws_size,
                              hipStream_t stream) {
    const int*   src = (const int*)d_in[0];
    const int*   dst = (const int*)d_in[1];
    const float* emb = (const float*)d_in[2];
    const float* W1  = (const float*)d_in[3];
    const float* b1  = (const float*)d_in[4];
    const float* W2  = (const float*)d_in[5];
    const float* b2  = (const float*)d_in[6];
    const float* W3  = (const float*)d_in[7];
    const float* b3  = (const float*)d_in[8];
    float* out = (float*)d_out;

    const int E  = in_sizes[0];
    const int Nn = in_sizes[2] / EMB;

    char* ws = (char*)d_ws;
    auto align256 = [](size_t x) { return (x + 255) & ~(size_t)255; };
    size_t p = 0;
    int* off    = (int*)(ws + p); p = align256(p + (size_t)(Nn + 1) * 4);
    int* cur    = (int*)(ws + p); p = align256(p + (size_t)(Nn + 1) * 4);
    int* sorted = (int*)(ws + p); p = align256(p + (size_t)E * 4);
    _Float16* buf0 = (_Float16*)(ws + p); p = align256(p + (size_t)Nn * HIDN * 2);
    _Float16* buf1 = (_Float16*)(ws + p); p = align256(p + (size_t)Nn * HIDN * 2);
    _Float16* Wt1  = (_Float16*)(ws + p); p = align256(p + (size_t)EMB * HIDN * 2);
    _Float16* Wt2  = (_Float16*)(ws + p); p = align256(p + (size_t)HIDN * HIDN * 2);
    _Float16* Wt3  = (_Float16*)(ws + p); p = align256(p + (size_t)HIDN * EMB * 2);

    // ---- CSR build (by dst) ----
    zero_i32<<<(Nn + 255) / 256, 256, 0, stream>>>(cur, Nn);
    hist_kernel<<<(E + 255) / 256, 256, 0, stream>>>(dst, E, cur);
    scan_kernel<<<1, 1024, 0, stream>>>(cur, off, Nn, E);
    scatter_kernel<<<(E + 255) / 256, 256, 0, stream>>>(src, dst, E, cur, sorted);

    // ---- weight prep ----
    transpose_f16<<<(EMB * HIDN + 255) / 256, 256, 0, stream>>>(W1, Wt1, EMB, HIDN);
    transpose_f16<<<(HIDN * HIDN + 255) / 256, 256, 0, stream>>>(W2, Wt2, HIDN, HIDN);
    transpose_f16<<<(HIDN * EMB + 255) / 256, 256, 0, stream>>>(W3, Wt3, HIDN, EMB);

    // ---- emb -> fp16 ----
    f32_to_f16<<<(Nn * EMB / 4 + 255) / 256, 256, 0, stream>>>(emb, buf0, Nn * EMB / 4);

    const int segBlocks = (Nn + 3) / 4;
    const int gmM = (Nn + 127) / 128;

    // ---- Layer 1: 128 -> 256, relu ----
    segmax_add_h<2><<<segBlocks, 256, 0, stream>>>(buf0, off, sorted, buf1, Nn);
    gemm_h<0, 1><<<dim3(gmM, 2), 256, 0, stream>>>(buf1, Wt1, b1, buf0, Nn, EMB, HIDN);

    // ---- Layer 2: 256 -> 256, relu ----
    segmax_add_h<4><<<segBlocks, 256, 0, stream>>>(buf0, off, sorted, buf1, Nn);
    gemm_h<0, 1><<<dim3(gmM, 2), 256, 0, stream>>>(buf1, Wt2, b2, buf0, Nn, HIDN, HIDN);

    // ---- Layer 3: 256 -> 128, no relu ----
    segmax_add_h<4><<<segBlocks, 256, 0, stream>>>(buf0, off, sorted, buf1, Nn);
    gemm_h<1, 0><<<dim3(gmM, 1), 256, 0, stream>>>(buf1, Wt3, b3, out, Nn, HIDN, EMB);
}

// Round 3
// 463.434 us; speedup vs baseline: 1.5883x; 1.2140x over previous
//
#include <hip/hip_runtime.h>
#include <math.h>

#define EMB 128
#define HIDN 256

typedef _Float16 half8 __attribute__((ext_vector_type(8)));
typedef _Float16 half4 __attribute__((ext_vector_type(4)));
typedef _Float16 half2v __attribute__((ext_vector_type(2)));
typedef float f32x4 __attribute__((ext_vector_type(4)));

// ---------------- CSR build ----------------

__global__ void zero_i32(int* p, int n) {
    int i = blockIdx.x * blockDim.x + threadIdx.x;
    if (i < n) p[i] = 0;
}

__global__ void hist_kernel(const int* __restrict__ dst, int E, int* __restrict__ cnt) {
    int i = blockIdx.x * blockDim.x + threadIdx.x;
    if (i < E) atomicAdd(&cnt[dst[i]], 1);
}

// --- hierarchical scan: 1024 elements per block ---

__global__ void scan_partial(const int* __restrict__ cnt, int* __restrict__ partials, int Nn) {
    __shared__ int red[256];
    const int b = blockIdx.x, t = threadIdx.x;
    const int base = b * 1024 + t * 4;
    int s = 0;
#pragma unroll
    for (int i = 0; i < 4; ++i)
        if (base + i < Nn) s += cnt[base + i];
    red[t] = s;
    __syncthreads();
    for (int d = 128; d > 0; d >>= 1) {
        if (t < d) red[t] += red[t + d];
        __syncthreads();
    }
    if (t == 0) partials[b] = red[0];
}

// single block, 256 threads: partials[i] <- exclusive prefix sum (nB <= 256)
__global__ void scan_top(int* __restrict__ partials, int nB) {
    __shared__ int s[256];
    const int t = threadIdx.x;
    int orig = (t < nB) ? partials[t] : 0;
    s[t] = orig;
    __syncthreads();
    for (int d = 1; d < 256; d <<= 1) {
        int v = (t >= d) ? s[t - d] : 0;
        __syncthreads();
        s[t] += v;
        __syncthreads();
    }
    if (t < nB) partials[t] = s[t] - orig;
}

__global__ void scan_apply(const int* __restrict__ cnt, const int* __restrict__ pbase,
                           int* __restrict__ off, int* __restrict__ cur, int Nn, int E) {
    __shared__ int tsum[256];
    const int b = blockIdx.x, t = threadIdx.x;
    const int base = b * 1024 + t * 4;
    int c[4];
#pragma unroll
    for (int i = 0; i < 4; ++i) c[i] = (base + i < Nn) ? cnt[base + i] : 0;
    int s = c[0] + c[1] + c[2] + c[3];
    tsum[t] = s;
    __syncthreads();
    for (int d = 1; d < 256; d <<= 1) {
        int v = (t >= d) ? tsum[t - d] : 0;
        __syncthreads();
        tsum[t] += v;
        __syncthreads();
    }
    int run = pbase[b] + ((t == 0) ? 0 : tsum[t - 1]);
#pragma unroll
    for (int i = 0; i < 4; ++i) {
        int idx = base + i;
        if (idx < Nn) {
            off[idx] = run;
            cur[idx] = run;
            run += c[i];
        }
    }
    if (b == 0 && t == 0) off[Nn] = E;
}

__global__ void scatter_kernel(const int* __restrict__ src, const int* __restrict__ dst,
                               int E, int* __restrict__ cur, int* __restrict__ sorted) {
    int i = blockIdx.x * blockDim.x + threadIdx.x;
    if (i < E) {
        int d = dst[i];
        int p = atomicAdd(&cur[d], 1);
        sorted[p] = src[i];
    }
}

// ---------------- dtype conversion helpers ----------------

__global__ void f32_to_f16(const float* __restrict__ in, _Float16* __restrict__ out, int n4) {
    int i = blockIdx.x * blockDim.x + threadIdx.x;
    if (i < n4) {
        float4 v = *reinterpret_cast<const float4*>(in + (size_t)i * 4);
        half4 h;
        h[0] = (_Float16)v.x; h[1] = (_Float16)v.y;
        h[2] = (_Float16)v.z; h[3] = (_Float16)v.w;
        *reinterpret_cast<half4*>(out + (size_t)i * 4) = h;
    }
}

// Wt[n*K + k] = (f16) W[k*N + n]
__global__ void transpose_f16(const float* __restrict__ W, _Float16* __restrict__ Wt, int K, int N) {
    int i = blockIdx.x * blockDim.x + threadIdx.x;
    if (i < K * N) {
        int k = i / N;
        int n = i - k * N;
        Wt[(size_t)n * K + k] = (_Float16)W[i];
    }
}

// ---------------- fused segment-max + self-add (fp16) ----------------

template <int VEC>
__global__ void segmax_add_h(const _Float16* __restrict__ x, const int* __restrict__ off,
                             const int* __restrict__ sorted, _Float16* __restrict__ xs, int Nn) {
    const int D = VEC * 64;
    const int node = blockIdx.x * (blockDim.x >> 6) + (threadIdx.x >> 6);
    const int lane = threadIdx.x & 63;
    if (node >= Nn) return;
    const int beg = off[node];
    const int end = off[node + 1];
    const int col = lane * VEC;

    float acc[VEC];
#pragma unroll
    for (int i = 0; i < VEC; ++i) acc[i] = -INFINITY;

    for (int e = beg; e < end; ++e) {
        int s = sorted[e];
        const _Float16* row = x + (size_t)s * D + col;
        if (VEC == 4) {
            half4 v = *reinterpret_cast<const half4*>(row);
#pragma unroll
            for (int i = 0; i < 4; ++i) acc[i] = fmaxf(acc[i], (float)v[i]);
        } else {
            half2v v = *reinterpret_cast<const half2v*>(row);
#pragma unroll
            for (int i = 0; i < 2; ++i) acc[i] = fmaxf(acc[i], (float)v[i]);
        }
    }

    const bool hasEdges = (end > beg);
    const _Float16* xr = x + (size_t)node * D + col;
    _Float16* outp = xs + (size_t)node * D + col;
    if (VEC == 4) {
        half4 xv = *reinterpret_cast<const half4*>(xr);
        half4 o;
#pragma unroll
        for (int i = 0; i < 4; ++i)
            o[i] = (_Float16)((float)xv[i] + (hasEdges ? acc[i] : 0.0f));
        *reinterpret_cast<half4*>(outp) = o;
    } else {
        half2v xv = *reinterpret_cast<const half2v*>(xr);
        half2v o;
#pragma unroll
        for (int i = 0; i < 2; ++i)
            o[i] = (_Float16)((float)xv[i] + (hasEdges ? acc[i] : 0.0f));
        *reinterpret_cast<half2v*>(outp) = o;
    }
}

// ---------------- MFMA fp16 GEMM ----------------
// C[M,N] = A[M,K] @ W[K,N] + bias (+ReLU). A fp16 row-major, Wt fp16 [N][K].
// BM=128, BN=128, BK=32. 256 threads = 4 waves (2x2), each wave 64x64 out.

template <int OUT_F32, int RELU>
__global__ __launch_bounds__(256) void gemm_h(
    const _Float16* __restrict__ A, const _Float16* __restrict__ Wt,
    const float* __restrict__ bias, void* __restrict__ C,
    int M, int K, int N)
{
    __shared__ _Float16 sA[4 * 128 * 8];
    __shared__ _Float16 sB[4 * 128 * 8];

    const int tid = threadIdx.x;
    const int r0 = blockIdx.x * 128;
    const int n0 = blockIdx.y * 128;

    const int wave = tid >> 6;
    const int lane = tid & 63;
    const int g = lane >> 4;
    const int r = lane & 15;
    const int m_base = (wave >> 1) * 64;
    const int n_base = (wave & 1) * 64;

    f32x4 acc[4][4];
#pragma unroll
    for (int i = 0; i < 4; ++i)
#pragma unroll
        for (int j = 0; j < 4; ++j) acc[i][j] = (f32x4){0.f, 0.f, 0.f, 0.f};

    for (int k0 = 0; k0 < K; k0 += 32) {
#pragma unroll
        for (int h = 0; h < 2; ++h) {
            int s = tid + h * 256;
            int row = s >> 2;
            int j = s & 3;
            int ar = r0 + row; ar = ar < M ? ar : (M - 1);
            half8 av = *reinterpret_cast<const half8*>(A + (size_t)ar * K + k0 + j * 8);
            *reinterpret_cast<half8*>(&sA[((j << 7) + row) << 3]) = av;
            half8 bv = *reinterpret_cast<const half8*>(Wt + (size_t)(n0 + row) * K + k0 + j * 8);
            *reinterpret_cast<half8*>(&sB[((j << 7) + row) << 3]) = bv;
        }
        __syncthreads();

        half8 aF[4], bF[4];
#pragma unroll
        for (int mi = 0; mi < 4; ++mi)
            aF[mi] = *reinterpret_cast<half8*>(&sA[((g << 7) + m_base + mi * 16 + r) << 3]);
#pragma unroll
        for (int ni = 0; ni < 4; ++ni)
            bF[ni] = *reinterpret_cast<half8*>(&sB[((g << 7) + n_base + ni * 16 + r) << 3]);

#pragma unroll
        for (int mi = 0; mi < 4; ++mi)
#pragma unroll
            for (int ni = 0; ni < 4; ++ni)
                acc[mi][ni] = __builtin_amdgcn_mfma_f32_16x16x32_f16(aF[mi], bF[ni], acc[mi][ni], 0, 0, 0);

        __syncthreads();
    }

#pragma unroll
    for (int ni = 0; ni < 4; ++ni) {
        int col = n0 + n_base + ni * 16 + r;
        float bv = bias[col];
#pragma unroll
        for (int mi = 0; mi < 4; ++mi) {
#pragma unroll
            for (int q = 0; q < 4; ++q) {
                int row = r0 + m_base + mi * 16 + g * 4 + q;
                if (row < M) {
                    float v = acc[mi][ni][q] + bv;
                    if (RELU) v = fmaxf(v, 0.f);
                    if (OUT_F32)
                        ((float*)C)[(size_t)row * N + col] = v;
                    else
                        ((_Float16*)C)[(size_t)row * N + col] = (_Float16)v;
                }
            }
        }
    }
}

// ---------------- launch ----------------

extern "C" void kernel_launch(void* const* d_in, const int* in_sizes, int n_in,
                              void* d_out, int out_size, void* d_ws, size_t ws_size,
                              hipStream_t stream) {
    const int*   src = (const int*)d_in[0];
    const int*   dst = (const int*)d_in[1];
    const float* emb = (const float*)d_in[2];
    const float* W1  = (const float*)d_in[3];
    const float* b1  = (const float*)d_in[4];
    const float* W2  = (const float*)d_in[5];
    const float* b2  = (const float*)d_in[6];
    const float* W3  = (const float*)d_in[7];
    const float* b3  = (const float*)d_in[8];
    float* out = (float*)d_out;

    const int E  = in_sizes[0];
    const int Nn = in_sizes[2] / EMB;

    char* ws = (char*)d_ws;
    auto align256 = [](size_t x) { return (x + 255) & ~(size_t)255; };
    size_t p = 0;
    int* off      = (int*)(ws + p); p = align256(p + (size_t)(Nn + 1) * 4);
    int* cur      = (int*)(ws + p); p = align256(p + (size_t)(Nn + 1) * 4);
    int* partials = (int*)(ws + p); p = align256(p + 256 * 4);
    int* sorted   = (int*)(ws + p); p = align256(p + (size_t)E * 4);
    _Float16* buf0 = (_Float16*)(ws + p); p = align256(p + (size_t)Nn * HIDN * 2);
    _Float16* buf1 = (_Float16*)(ws + p); p = align256(p + (size_t)Nn * HIDN * 2);
    _Float16* Wt1  = (_Float16*)(ws + p); p = align256(p + (size_t)EMB * HIDN * 2);
    _Float16* Wt2  = (_Float16*)(ws + p); p = align256(p + (size_t)HIDN * HIDN * 2);
    _Float16* Wt3  = (_Float16*)(ws + p); p = align256(p + (size_t)HIDN * EMB * 2);

    // ---- CSR build (by dst) ----
    const int nScanBlocks = (Nn + 1023) / 1024;  // 49 for Nn=50000 (<=256 supported)
    zero_i32<<<(Nn + 255) / 256, 256, 0, stream>>>(cur, Nn);
    hist_kernel<<<(E + 255) / 256, 256, 0, stream>>>(dst, E, cur);
    scan_partial<<<nScanBlocks, 256, 0, stream>>>(cur, partials, Nn);
    scan_top<<<1, 256, 0, stream>>>(partials, nScanBlocks);
    scan_apply<<<nScanBlocks, 256, 0, stream>>>(cur, partials, off, cur, Nn, E);
    scatter_kernel<<<(E + 255) / 256, 256, 0, stream>>>(src, dst, E, cur, sorted);

    // ---- weight prep ----
    transpose_f16<<<(EMB * HIDN + 255) / 256, 256, 0, stream>>>(W1, Wt1, EMB, HIDN);
    transpose_f16<<<(HIDN * HIDN + 255) / 256, 256, 0, stream>>>(W2, Wt2, HIDN, HIDN);
    transpose_f16<<<(HIDN * EMB + 255) / 256, 256, 0, stream>>>(W3, Wt3, HIDN, EMB);

    // ---- emb -> fp16 ----
    f32_to_f16<<<(Nn * EMB / 4 + 255) / 256, 256, 0, stream>>>(emb, buf0, Nn * EMB / 4);

    const int segBlocks = (Nn + 3) / 4;
    const int gmM = (Nn + 127) / 128;

    // ---- Layer 1: 128 -> 256, relu ----
    segmax_add_h<2><<<segBlocks, 256, 0, stream>>>(buf0, off, sorted, buf1, Nn);
    gemm_h<0, 1><<<dim3(gmM, 2), 256, 0, stream>>>(buf1, Wt1, b1, buf0, Nn, EMB, HIDN);

    // ---- Layer 2: 256 -> 256, relu ----
    segmax_add_h<4><<<segBlocks, 256, 0, stream>>>(buf0, off, sorted, buf1, Nn);
    gemm_h<0, 1><<<dim3(gmM, 2), 256, 0, stream>>>(buf1, Wt2, b2, buf0, Nn, HIDN, HIDN);

    // ---- Layer 3: 256 -> 128, no relu ----
    segmax_add_h<4><<<segBlocks, 256, 0, stream>>>(buf0, off, sorted, buf1, Nn);
    gemm_h<1, 0><<<dim3(gmM, 1), 256, 0, stream>>>(buf1, Wt3, b3, out, Nn, HIDN, EMB);
}

// Round 4
// 384.513 us; speedup vs baseline: 1.9143x; 1.2052x over previous
//
#include <hip/hip_runtime.h>
#include <math.h>

#define EMB 128
#define HIDN 256

typedef _Float16 half8 __attribute__((ext_vector_type(8)));
typedef _Float16 half4 __attribute__((ext_vector_type(4)));
typedef _Float16 half2v __attribute__((ext_vector_type(2)));
typedef float f32x4 __attribute__((ext_vector_type(4)));

// ---------------- CSR build ----------------

__global__ void zero_i32(int* p, int n) {
    int i = blockIdx.x * blockDim.x + threadIdx.x;
    if (i < n) p[i] = 0;
}

__global__ void hist_kernel(const int* __restrict__ dst, int E, int* __restrict__ cnt) {
    int i = blockIdx.x * blockDim.x + threadIdx.x;
    if (i < E) atomicAdd(&cnt[dst[i]], 1);
}

// --- hierarchical scan: 1024 elements per block ---

__global__ void scan_partial(const int* __restrict__ cnt, int* __restrict__ partials, int Nn) {
    __shared__ int red[256];
    const int b = blockIdx.x, t = threadIdx.x;
    const int base = b * 1024 + t * 4;
    int s = 0;
#pragma unroll
    for (int i = 0; i < 4; ++i)
        if (base + i < Nn) s += cnt[base + i];
    red[t] = s;
    __syncthreads();
    for (int d = 128; d > 0; d >>= 1) {
        if (t < d) red[t] += red[t + d];
        __syncthreads();
    }
    if (t == 0) partials[b] = red[0];
}

__global__ void scan_top(int* __restrict__ partials, int nB) {
    __shared__ int s[256];
    const int t = threadIdx.x;
    int orig = (t < nB) ? partials[t] : 0;
    s[t] = orig;
    __syncthreads();
    for (int d = 1; d < 256; d <<= 1) {
        int v = (t >= d) ? s[t - d] : 0;
        __syncthreads();
        s[t] += v;
        __syncthreads();
    }
    if (t < nB) partials[t] = s[t] - orig;
}

__global__ void scan_apply(const int* __restrict__ cnt, const int* __restrict__ pbase,
                           int* __restrict__ off, int* __restrict__ cur, int Nn, int E) {
    __shared__ int tsum[256];
    const int b = blockIdx.x, t = threadIdx.x;
    const int base = b * 1024 + t * 4;
    int c[4];
#pragma unroll
    for (int i = 0; i < 4; ++i) c[i] = (base + i < Nn) ? cnt[base + i] : 0;
    int s = c[0] + c[1] + c[2] + c[3];
    tsum[t] = s;
    __syncthreads();
    for (int d = 1; d < 256; d <<= 1) {
        int v = (t >= d) ? tsum[t - d] : 0;
        __syncthreads();
        tsum[t] += v;
        __syncthreads();
    }
    int run = pbase[b] + ((t == 0) ? 0 : tsum[t - 1]);
#pragma unroll
    for (int i = 0; i < 4; ++i) {
        int idx = base + i;
        if (idx < Nn) {
            off[idx] = run;
            cur[idx] = run;
            run += c[i];
        }
    }
    if (b == 0 && t == 0) off[Nn] = E;
}

__global__ void scatter_kernel(const int* __restrict__ src, const int* __restrict__ dst,
                               int E, int* __restrict__ cur, int* __restrict__ sorted) {
    int i = blockIdx.x * blockDim.x + threadIdx.x;
    if (i < E) {
        int d = dst[i];
        int p = atomicAdd(&cur[d], 1);
        sorted[p] = src[i];
    }
}

// ---------------- dtype conversion helpers ----------------

__global__ void f32_to_f16(const float* __restrict__ in, _Float16* __restrict__ out, int n4) {
    int i = blockIdx.x * blockDim.x + threadIdx.x;
    if (i < n4) {
        float4 v = *reinterpret_cast<const float4*>(in + (size_t)i * 4);
        half4 h;
        h[0] = (_Float16)v.x; h[1] = (_Float16)v.y;
        h[2] = (_Float16)v.z; h[3] = (_Float16)v.w;
        *reinterpret_cast<half4*>(out + (size_t)i * 4) = h;
    }
}

// Wt[n*K + k] = (f16) W[k*N + n]
__global__ void transpose_f16(const float* __restrict__ W, _Float16* __restrict__ Wt, int K, int N) {
    int i = blockIdx.x * blockDim.x + threadIdx.x;
    if (i < K * N) {
        int k = i / N;
        int n = i - k * N;
        Wt[(size_t)n * K + k] = (_Float16)W[i];
    }
}

// ---------------- fused segment-max + self-add (fp16) ----------------
// One wave per node. Indices batched: one coalesced load of up to 64 neighbor
// ids per wave, broadcast via __shfl; row gathers unrolled x4 for MLP.

template <int VEC>
__global__ void segmax_add_h(const _Float16* __restrict__ x, const int* __restrict__ off,
                             const int* __restrict__ sorted, _Float16* __restrict__ xs, int Nn) {
    const int D = VEC * 64;
    const int node = blockIdx.x * (blockDim.x >> 6) + (threadIdx.x >> 6);
    const int lane = threadIdx.x & 63;
    if (node >= Nn) return;
    const int beg = off[node];
    const int end = off[node + 1];
    const int col = lane * VEC;
    const _Float16* xcol = x + col;

    float acc[VEC];
#pragma unroll
    for (int i = 0; i < VEC; ++i) acc[i] = -INFINITY;

    for (int eb = beg; eb < end; eb += 64) {
        const int cnt = min(64, end - eb);
        // one coalesced index load for up to 64 edges
        int myIdx = sorted[eb + (lane < cnt ? lane : cnt - 1)];
#pragma unroll 4
        for (int j = 0; j < cnt; ++j) {
            int s = __shfl(myIdx, j);
            const _Float16* row = xcol + (size_t)s * D;
            if (VEC == 4) {
                half4 v = *reinterpret_cast<const half4*>(row);
#pragma unroll
                for (int i = 0; i < 4; ++i) acc[i] = fmaxf(acc[i], (float)v[i]);
            } else {
                half2v v = *reinterpret_cast<const half2v*>(row);
#pragma unroll
                for (int i = 0; i < 2; ++i) acc[i] = fmaxf(acc[i], (float)v[i]);
            }
        }
    }

    const bool hasEdges = (end > beg);
    const _Float16* xr = xcol + (size_t)node * D;
    _Float16* outp = xs + (size_t)node * D + col;
    if (VEC == 4) {
        half4 xv = *reinterpret_cast<const half4*>(xr);
        half4 o;
#pragma unroll
        for (int i = 0; i < 4; ++i)
            o[i] = (_Float16)((float)xv[i] + (hasEdges ? acc[i] : 0.0f));
        *reinterpret_cast<half4*>(outp) = o;
    } else {
        half2v xv = *reinterpret_cast<const half2v*>(xr);
        half2v o;
#pragma unroll
        for (int i = 0; i < 2; ++i)
            o[i] = (_Float16)((float)xv[i] + (hasEdges ? acc[i] : 0.0f));
        *reinterpret_cast<half2v*>(outp) = o;
    }
}

// ---------------- MFMA fp16 GEMM ----------------
// C[M,N] = A[M,K] @ W[K,N] + bias (+ReLU). A fp16 row-major, Wt fp16 [N][K].
// BM=128, BN=128, BK=32. 256 threads = 4 waves (2x2), each wave 64x64 out.

template <int OUT_F32, int RELU>
__global__ __launch_bounds__(256) void gemm_h(
    const _Float16* __restrict__ A, const _Float16* __restrict__ Wt,
    const float* __restrict__ bias, void* __restrict__ C,
    int M, int K, int N)
{
    __shared__ _Float16 sA[4 * 128 * 8];
    __shared__ _Float16 sB[4 * 128 * 8];

    const int tid = threadIdx.x;
    const int r0 = blockIdx.x * 128;
    const int n0 = blockIdx.y * 128;

    const int wave = tid >> 6;
    const int lane = tid & 63;
    const int g = lane >> 4;
    const int r = lane & 15;
    const int m_base = (wave >> 1) * 64;
    const int n_base = (wave & 1) * 64;

    f32x4 acc[4][4];
#pragma unroll
    for (int i = 0; i < 4; ++i)
#pragma unroll
        for (int j = 0; j < 4; ++j) acc[i][j] = (f32x4){0.f, 0.f, 0.f, 0.f};

    for (int k0 = 0; k0 < K; k0 += 32) {
#pragma unroll
        for (int h = 0; h < 2; ++h) {
            int s = tid + h * 256;
            int row = s >> 2;
            int j = s & 3;
            int ar = r0 + row; ar = ar < M ? ar : (M - 1);
            half8 av = *reinterpret_cast<const half8*>(A + (size_t)ar * K + k0 + j * 8);
            *reinterpret_cast<half8*>(&sA[((j << 7) + row) << 3]) = av;
            half8 bv = *reinterpret_cast<const half8*>(Wt + (size_t)(n0 + row) * K + k0 + j * 8);
            *reinterpret_cast<half8*>(&sB[((j << 7) + row) << 3]) = bv;
        }
        __syncthreads();

        half8 aF[4], bF[4];
#pragma unroll
        for (int mi = 0; mi < 4; ++mi)
            aF[mi] = *reinterpret_cast<half8*>(&sA[((g << 7) + m_base + mi * 16 + r) << 3]);
#pragma unroll
        for (int ni = 0; ni < 4; ++ni)
            bF[ni] = *reinterpret_cast<half8*>(&sB[((g << 7) + n_base + ni * 16 + r) << 3]);

#pragma unroll
        for (int mi = 0; mi < 4; ++mi)
#pragma unroll
            for (int ni = 0; ni < 4; ++ni)
                acc[mi][ni] = __builtin_amdgcn_mfma_f32_16x16x32_f16(aF[mi], bF[ni], acc[mi][ni], 0, 0, 0);

        __syncthreads();
    }

#pragma unroll
    for (int ni = 0; ni < 4; ++ni) {
        int col = n0 + n_base + ni * 16 + r;
        float bv = bias[col];
#pragma unroll
        for (int mi = 0; mi < 4; ++mi) {
#pragma unroll
            for (int q = 0; q < 4; ++q) {
                int row = r0 + m_base + mi * 16 + g * 4 + q;
                if (row < M) {
                    float v = acc[mi][ni][q] + bv;
                    if (RELU) v = fmaxf(v, 0.f);
                    if (OUT_F32)
                        ((float*)C)[(size_t)row * N + col] = v;
                    else
                        ((_Float16*)C)[(size_t)row * N + col] = (_Float16)v;
                }
            }
        }
    }
}

// ---------------- launch ----------------

extern "C" void kernel_launch(void* const* d_in, const int* in_sizes, int n_in,
                              void* d_out, int out_size, void* d_ws, size_t ws_size,
                              hipStream_t stream) {
    const int*   src = (const int*)d_in[0];
    const int*   dst = (const int*)d_in[1];
    const float* emb = (const float*)d_in[2];
    const float* W1  = (const float*)d_in[3];
    const float* b1  = (const float*)d_in[4];
    const float* W2  = (const float*)d_in[5];
    const float* b2  = (const float*)d_in[6];
    const float* W3  = (const float*)d_in[7];
    const float* b3  = (const float*)d_in[8];
    float* out = (float*)d_out;

    const int E  = in_sizes[0];
    const int Nn = in_sizes[2] / EMB;

    char* ws = (char*)d_ws;
    auto align256 = [](size_t x) { return (x + 255) & ~(size_t)255; };
    size_t p = 0;
    int* off      = (int*)(ws + p); p = align256(p + (size_t)(Nn + 1) * 4);
    int* cur      = (int*)(ws + p); p = align256(p + (size_t)(Nn + 1) * 4);
    int* partials = (int*)(ws + p); p = align256(p + 256 * 4);
    int* sorted   = (int*)(ws + p); p = align256(p + (size_t)E * 4);
    _Float16* buf0 = (_Float16*)(ws + p); p = align256(p + (size_t)Nn * HIDN * 2);
    _Float16* buf1 = (_Float16*)(ws + p); p = align256(p + (size_t)Nn * HIDN * 2);
    _Float16* Wt1  = (_Float16*)(ws + p); p = align256(p + (size_t)EMB * HIDN * 2);
    _Float16* Wt2  = (_Float16*)(ws + p); p = align256(p + (size_t)HIDN * HIDN * 2);
    _Float16* Wt3  = (_Float16*)(ws + p); p = align256(p + (size_t)HIDN * EMB * 2);

    // ---- CSR build (by dst) ----
    const int nScanBlocks = (Nn + 1023) / 1024;
    zero_i32<<<(Nn + 255) / 256, 256, 0, stream>>>(cur, Nn);
    hist_kernel<<<(E + 255) / 256, 256, 0, stream>>>(dst, E, cur);
    scan_partial<<<nScanBlocks, 256, 0, stream>>>(cur, partials, Nn);
    scan_top<<<1, 256, 0, stream>>>(partials, nScanBlocks);
    scan_apply<<<nScanBlocks, 256, 0, stream>>>(cur, partials, off, cur, Nn, E);
    scatter_kernel<<<(E + 255) / 256, 256, 0, stream>>>(src, dst, E, cur, sorted);

    // ---- weight prep ----
    transpose_f16<<<(EMB * HIDN + 255) / 256, 256, 0, stream>>>(W1, Wt1, EMB, HIDN);
    transpose_f16<<<(HIDN * HIDN + 255) / 256, 256, 0, stream>>>(W2, Wt2, HIDN, HIDN);
    transpose_f16<<<(HIDN * EMB + 255) / 256, 256, 0, stream>>>(W3, Wt3, HIDN, EMB);

    // ---- emb -> fp16 ----
    f32_to_f16<<<(Nn * EMB / 4 + 255) / 256, 256, 0, stream>>>(emb, buf0, Nn * EMB / 4);

    const int segBlocks = (Nn + 3) / 4;
    const int gmM = (Nn + 127) / 128;

    // ---- Layer 1: 128 -> 256, relu ----
    segmax_add_h<2><<<segBlocks, 256, 0, stream>>>(buf0, off, sorted, buf1, Nn);
    gemm_h<0, 1><<<dim3(gmM, 2), 256, 0, stream>>>(buf1, Wt1, b1, buf0, Nn, EMB, HIDN);

    // ---- Layer 2: 256 -> 256, relu ----
    segmax_add_h<4><<<segBlocks, 256, 0, stream>>>(buf0, off, sorted, buf1, Nn);
    gemm_h<0, 1><<<dim3(gmM, 2), 256, 0, stream>>>(buf1, Wt2, b2, buf0, Nn, HIDN, HIDN);

    // ---- Layer 3: 256 -> 128, no relu ----
    segmax_add_h<4><<<segBlocks, 256, 0, stream>>>(buf0, off, sorted, buf1, Nn);
    gemm_h<1, 0><<<dim3(gmM, 1), 256, 0, stream>>>(buf1, Wt3, b3, out, Nn, HIDN, EMB);
}

// Round 5
// 350.808 us; speedup vs baseline: 2.0982x; 1.0961x over previous
//
#include <hip/hip_runtime.h>
#include <math.h>

#define EMB 128
#define HIDN 256

typedef _Float16 half8 __attribute__((ext_vector_type(8)));
typedef _Float16 half4 __attribute__((ext_vector_type(4)));
typedef float f32x4 __attribute__((ext_vector_type(4)));

// ---------------- CSR build ----------------

__global__ void zero_i32(int* p, int n) {
    int i = blockIdx.x * blockDim.x + threadIdx.x;
    if (i < n) p[i] = 0;
}

__global__ void hist_kernel(const int* __restrict__ dst, int E, int* __restrict__ cnt) {
    int i = blockIdx.x * blockDim.x + threadIdx.x;
    if (i < E) atomicAdd(&cnt[dst[i]], 1);
}

// --- hierarchical scan: 1024 elements per block ---

__global__ void scan_partial(const int* __restrict__ cnt, int* __restrict__ partials, int Nn) {
    __shared__ int red[256];
    const int b = blockIdx.x, t = threadIdx.x;
    const int base = b * 1024 + t * 4;
    int s = 0;
#pragma unroll
    for (int i = 0; i < 4; ++i)
        if (base + i < Nn) s += cnt[base + i];
    red[t] = s;
    __syncthreads();
    for (int d = 128; d > 0; d >>= 1) {
        if (t < d) red[t] += red[t + d];
        __syncthreads();
    }
    if (t == 0) partials[b] = red[0];
}

__global__ void scan_top(int* __restrict__ partials, int nB) {
    __shared__ int s[256];
    const int t = threadIdx.x;
    int orig = (t < nB) ? partials[t] : 0;
    s[t] = orig;
    __syncthreads();
    for (int d = 1; d < 256; d <<= 1) {
        int v = (t >= d) ? s[t - d] : 0;
        __syncthreads();
        s[t] += v;
        __syncthreads();
    }
    if (t < nB) partials[t] = s[t] - orig;
}

__global__ void scan_apply(const int* __restrict__ cnt, const int* __restrict__ pbase,
                           int* __restrict__ off, int* __restrict__ cur, int Nn, int E) {
    __shared__ int tsum[256];
    const int b = blockIdx.x, t = threadIdx.x;
    const int base = b * 1024 + t * 4;
    int c[4];
#pragma unroll
    for (int i = 0; i < 4; ++i) c[i] = (base + i < Nn) ? cnt[base + i] : 0;
    int s = c[0] + c[1] + c[2] + c[3];
    tsum[t] = s;
    __syncthreads();
    for (int d = 1; d < 256; d <<= 1) {
        int v = (t >= d) ? tsum[t - d] : 0;
        __syncthreads();
        tsum[t] += v;
        __syncthreads();
    }
    int run = pbase[b] + ((t == 0) ? 0 : tsum[t - 1]);
#pragma unroll
    for (int i = 0; i < 4; ++i) {
        int idx = base + i;
        if (idx < Nn) {
            off[idx] = run;
            cur[idx] = run;
            run += c[i];
        }
    }
    if (b == 0 && t == 0) off[Nn] = E;
}

__global__ void scatter_kernel(const int* __restrict__ src, const int* __restrict__ dst,
                               int E, int* __restrict__ cur, int* __restrict__ sorted) {
    int i = blockIdx.x * blockDim.x + threadIdx.x;
    if (i < E) {
        int d = dst[i];
        int p = atomicAdd(&cur[d], 1);
        sorted[p] = src[i];
    }
}

// ---------------- dtype conversion helpers ----------------

__global__ void f32_to_f16(const float* __restrict__ in, _Float16* __restrict__ out, int n4) {
    int i = blockIdx.x * blockDim.x + threadIdx.x;
    if (i < n4) {
        float4 v = *reinterpret_cast<const float4*>(in + (size_t)i * 4);
        half4 h;
        h[0] = (_Float16)v.x; h[1] = (_Float16)v.y;
        h[2] = (_Float16)v.z; h[3] = (_Float16)v.w;
        *reinterpret_cast<half4*>(out + (size_t)i * 4) = h;
    }
}

// Wt[n*K + k] = (f16) W[k*N + n]
__global__ void transpose_f16(const float* __restrict__ W, _Float16* __restrict__ Wt, int K, int N) {
    int i = blockIdx.x * blockDim.x + threadIdx.x;
    if (i < K * N) {
        int k = i / N;
        int n = i - k * N;
        Wt[(size_t)n * K + k] = (_Float16)W[i];
    }
}

// ---------------- fused segment-max + self-add (fp16, packed max) ----------------
// One wave per node. Lane holds half8 (16B). NG edge streams per wave
// (NG = 64*8/D). Per batch: one coalesced 64-index load, __shfl broadcast.
// OOB stream slots clamp to last edge (max idempotent) -> branch-free.

template <int VEC>
__global__ void segmax_add_h(const _Float16* __restrict__ x, const int* __restrict__ off,
                             const int* __restrict__ sorted, _Float16* __restrict__ xs, int Nn) {
    const int D = VEC * 64;
    const int NG = (VEC == 4) ? 2 : 4;   // concurrent edge streams
    const int LPR = 64 / NG;             // lanes per row
    const int node = blockIdx.x * (blockDim.x >> 6) + (threadIdx.x >> 6);
    const int lane = threadIdx.x & 63;
    if (node >= Nn) return;
    const int g = lane / LPR;
    const int col = (lane % LPR) * 8;
    const int beg = off[node];
    const int end = off[node + 1];
    const _Float16* xcol = x + col;

    half8 acc;
#pragma unroll
    for (int i = 0; i < 8; ++i) acc[i] = (_Float16)(-INFINITY);

    for (int eb = beg; eb < end; eb += 64) {
        const int cnt = min(64, end - eb);
        // one coalesced index load; lanes >= cnt duplicate the last edge
        int myIdx = sorted[eb + (lane < cnt ? lane : cnt - 1)];
        const int nj = (cnt + NG - 1) / NG;
#pragma unroll 4
        for (int j = 0; j < nj; ++j) {
            int s = __shfl(myIdx, j * NG + g);  // srcLane <= 63 always
            half8 v = *reinterpret_cast<const half8*>(xcol + (size_t)s * D);
            acc = __builtin_elementwise_max(acc, v);
        }
    }

    // combine across edge streams (same columns in every group)
    union U { half8 h; int i[4]; };
    if (NG == 4) {
        U a, b; a.h = acc;
#pragma unroll
        for (int k = 0; k < 4; ++k) b.i[k] = __shfl_xor(a.i[k], 16);
        acc = __builtin_elementwise_max(a.h, b.h);
    }
    {
        U a, b; a.h = acc;
#pragma unroll
        for (int k = 0; k < 4; ++k) b.i[k] = __shfl_xor(a.i[k], 32);
        acc = __builtin_elementwise_max(a.h, b.h);
    }

    if (g == 0) {
        const bool hasEdges = (end > beg);
        half8 xv = *reinterpret_cast<const half8*>(xcol + (size_t)node * D);
        half8 o;
#pragma unroll
        for (int i = 0; i < 8; ++i)
            o[i] = (_Float16)((float)xv[i] + (hasEdges ? (float)acc[i] : 0.0f));
        *reinterpret_cast<half8*>(xs + (size_t)node * D + col) = o;
    }
}

// ---------------- MFMA fp16 GEMM ----------------
// C[M,N] = A[M,K] @ W[K,N] + bias (+ReLU). A fp16 row-major, Wt fp16 [N][K].
// BM=128, BN=128, BK=32. 256 threads = 4 waves (2x2), each wave 64x64 out.

template <int OUT_F32, int RELU>
__global__ __launch_bounds__(256) void gemm_h(
    const _Float16* __restrict__ A, const _Float16* __restrict__ Wt,
    const float* __restrict__ bias, void* __restrict__ C,
    int M, int K, int N)
{
    __shared__ _Float16 sA[4 * 128 * 8];
    __shared__ _Float16 sB[4 * 128 * 8];

    const int tid = threadIdx.x;
    const int r0 = blockIdx.x * 128;
    const int n0 = blockIdx.y * 128;

    const int wave = tid >> 6;
    const int lane = tid & 63;
    const int g = lane >> 4;
    const int r = lane & 15;
    const int m_base = (wave >> 1) * 64;
    const int n_base = (wave & 1) * 64;

    f32x4 acc[4][4];
#pragma unroll
    for (int i = 0; i < 4; ++i)
#pragma unroll
        for (int j = 0; j < 4; ++j) acc[i][j] = (f32x4){0.f, 0.f, 0.f, 0.f};

    for (int k0 = 0; k0 < K; k0 += 32) {
#pragma unroll
        for (int h = 0; h < 2; ++h) {
            int s = tid + h * 256;
            int row = s >> 2;
            int j = s & 3;
            int ar = r0 + row; ar = ar < M ? ar : (M - 1);
            half8 av = *reinterpret_cast<const half8*>(A + (size_t)ar * K + k0 + j * 8);
            *reinterpret_cast<half8*>(&sA[((j << 7) + row) << 3]) = av;
            half8 bv = *reinterpret_cast<const half8*>(Wt + (size_t)(n0 + row) * K + k0 + j * 8);
            *reinterpret_cast<half8*>(&sB[((j << 7) + row) << 3]) = bv;
        }
        __syncthreads();

        half8 aF[4], bF[4];
#pragma unroll
        for (int mi = 0; mi < 4; ++mi)
            aF[mi] = *reinterpret_cast<half8*>(&sA[((g << 7) + m_base + mi * 16 + r) << 3]);
#pragma unroll
        for (int ni = 0; ni < 4; ++ni)
            bF[ni] = *reinterpret_cast<half8*>(&sB[((g << 7) + n_base + ni * 16 + r) << 3]);

#pragma unroll
        for (int mi = 0; mi < 4; ++mi)
#pragma unroll
            for (int ni = 0; ni < 4; ++ni)
                acc[mi][ni] = __builtin_amdgcn_mfma_f32_16x16x32_f16(aF[mi], bF[ni], acc[mi][ni], 0, 0, 0);

        __syncthreads();
    }

#pragma unroll
    for (int ni = 0; ni < 4; ++ni) {
        int col = n0 + n_base + ni * 16 + r;
        float bv = bias[col];
#pragma unroll
        for (int mi = 0; mi < 4; ++mi) {
#pragma unroll
            for (int q = 0; q < 4; ++q) {
                int row = r0 + m_base + mi * 16 + g * 4 + q;
                if (row < M) {
                    float v = acc[mi][ni][q] + bv;
                    if (RELU) v = fmaxf(v, 0.f);
                    if (OUT_F32)
                        ((float*)C)[(size_t)row * N + col] = v;
                    else
                        ((_Float16*)C)[(size_t)row * N + col] = (_Float16)v;
                }
            }
        }
    }
}

// ---------------- launch ----------------

extern "C" void kernel_launch(void* const* d_in, const int* in_sizes, int n_in,
                              void* d_out, int out_size, void* d_ws, size_t ws_size,
                              hipStream_t stream) {
    const int*   src = (const int*)d_in[0];
    const int*   dst = (const int*)d_in[1];
    const float* emb = (const float*)d_in[2];
    const float* W1  = (const float*)d_in[3];
    const float* b1  = (const float*)d_in[4];
    const float* W2  = (const float*)d_in[5];
    const float* b2  = (const float*)d_in[6];
    const float* W3  = (const float*)d_in[7];
    const float* b3  = (const float*)d_in[8];
    float* out = (float*)d_out;

    const int E  = in_sizes[0];
    const int Nn = in_sizes[2] / EMB;

    char* ws = (char*)d_ws;
    auto align256 = [](size_t x) { return (x + 255) & ~(size_t)255; };
    size_t p = 0;
    int* off      = (int*)(ws + p); p = align256(p + (size_t)(Nn + 1) * 4);
    int* cur      = (int*)(ws + p); p = align256(p + (size_t)(Nn + 1) * 4);
    int* partials = (int*)(ws + p); p = align256(p + 256 * 4);
    int* sorted   = (int*)(ws + p); p = align256(p + (size_t)E * 4);
    _Float16* buf0 = (_Float16*)(ws + p); p = align256(p + (size_t)Nn * HIDN * 2);
    _Float16* buf1 = (_Float16*)(ws + p); p = align256(p + (size_t)Nn * HIDN * 2);
    _Float16* Wt1  = (_Float16*)(ws + p); p = align256(p + (size_t)EMB * HIDN * 2);
    _Float16* Wt2  = (_Float16*)(ws + p); p = align256(p + (size_t)HIDN * HIDN * 2);
    _Float16* Wt3  = (_Float16*)(ws + p); p = align256(p + (size_t)HIDN * EMB * 2);

    // ---- CSR build (by dst) ----
    const int nScanBlocks = (Nn + 1023) / 1024;
    zero_i32<<<(Nn + 255) / 256, 256, 0, stream>>>(cur, Nn);
    hist_kernel<<<(E + 255) / 256, 256, 0, stream>>>(dst, E, cur);
    scan_partial<<<nScanBlocks, 256, 0, stream>>>(cur, partials, Nn);
    scan_top<<<1, 256, 0, stream>>>(partials, nScanBlocks);
    scan_apply<<<nScanBlocks, 256, 0, stream>>>(cur, partials, off, cur, Nn, E);
    scatter_kernel<<<(E + 255) / 256, 256, 0, stream>>>(src, dst, E, cur, sorted);

    // ---- weight prep ----
    transpose_f16<<<(EMB * HIDN + 255) / 256, 256, 0, stream>>>(W1, Wt1, EMB, HIDN);
    transpose_f16<<<(HIDN * HIDN + 255) / 256, 256, 0, stream>>>(W2, Wt2, HIDN, HIDN);
    transpose_f16<<<(HIDN * EMB + 255) / 256, 256, 0, stream>>>(W3, Wt3, HIDN, EMB);

    // ---- emb -> fp16 ----
    f32_to_f16<<<(Nn * EMB / 4 + 255) / 256, 256, 0, stream>>>(emb, buf0, Nn * EMB / 4);

    const int segBlocks = (Nn + 3) / 4;
    const int gmM = (Nn + 127) / 128;

    // ---- Layer 1: 128 -> 256, relu ----
    segmax_add_h<2><<<segBlocks, 256, 0, stream>>>(buf0, off, sorted, buf1, Nn);
    gemm_h<0, 1><<<dim3(gmM, 2), 256, 0, stream>>>(buf1, Wt1, b1, buf0, Nn, EMB, HIDN);

    // ---- Layer 2: 256 -> 256, relu ----
    segmax_add_h<4><<<segBlocks, 256, 0, stream>>>(buf0, off, sorted, buf1, Nn);
    gemm_h<0, 1><<<dim3(gmM, 2), 256, 0, stream>>>(buf1, Wt2, b2, buf0, Nn, HIDN, HIDN);

    // ---- Layer 3: 256 -> 128, no relu ----
    segmax_add_h<4><<<segBlocks, 256, 0, stream>>>(buf0, off, sorted, buf1, Nn);
    gemm_h<1, 0><<<dim3(gmM, 1), 256, 0, stream>>>(buf1, Wt3, b3, out, Nn, HIDN, EMB);
}

// Round 6
// 342.719 us; speedup vs baseline: 2.1478x; 1.0236x over previous
//
#include <hip/hip_runtime.h>
#include <math.h>

#define EMB 128
#define HIDN 256

typedef _Float16 half8 __attribute__((ext_vector_type(8)));
typedef _Float16 half4 __attribute__((ext_vector_type(4)));
typedef float f32x4 __attribute__((ext_vector_type(4)));

// ---------------- CSR build ----------------

__global__ void zero_i32(int* p, int n) {
    int i = blockIdx.x * blockDim.x + threadIdx.x;
    if (i < n) p[i] = 0;
}

__global__ void hist_kernel(const int* __restrict__ dst, int E, int* __restrict__ cnt) {
    int i = blockIdx.x * blockDim.x + threadIdx.x;
    if (i < E) atomicAdd(&cnt[dst[i]], 1);
}

__global__ void scan_partial(const int* __restrict__ cnt, int* __restrict__ partials, int Nn) {
    __shared__ int red[256];
    const int b = blockIdx.x, t = threadIdx.x;
    const int base = b * 1024 + t * 4;
    int s = 0;
#pragma unroll
    for (int i = 0; i < 4; ++i)
        if (base + i < Nn) s += cnt[base + i];
    red[t] = s;
    __syncthreads();
    for (int d = 128; d > 0; d >>= 1) {
        if (t < d) red[t] += red[t + d];
        __syncthreads();
    }
    if (t == 0) partials[b] = red[0];
}

__global__ void scan_top(int* __restrict__ partials, int nB) {
    __shared__ int s[256];
    const int t = threadIdx.x;
    int orig = (t < nB) ? partials[t] : 0;
    s[t] = orig;
    __syncthreads();
    for (int d = 1; d < 256; d <<= 1) {
        int v = (t >= d) ? s[t - d] : 0;
        __syncthreads();
        s[t] += v;
        __syncthreads();
    }
    if (t < nB) partials[t] = s[t] - orig;
}

__global__ void scan_apply(const int* __restrict__ cnt, const int* __restrict__ pbase,
                           int* __restrict__ off, int* __restrict__ cur, int Nn, int E) {
    __shared__ int tsum[256];
    const int b = blockIdx.x, t = threadIdx.x;
    const int base = b * 1024 + t * 4;
    int c[4];
#pragma unroll
    for (int i = 0; i < 4; ++i) c[i] = (base + i < Nn) ? cnt[base + i] : 0;
    int s = c[0] + c[1] + c[2] + c[3];
    tsum[t] = s;
    __syncthreads();
    for (int d = 1; d < 256; d <<= 1) {
        int v = (t >= d) ? tsum[t - d] : 0;
        __syncthreads();
        tsum[t] += v;
        __syncthreads();
    }
    int run = pbase[b] + ((t == 0) ? 0 : tsum[t - 1]);
#pragma unroll
    for (int i = 0; i < 4; ++i) {
        int idx = base + i;
        if (idx < Nn) {
            off[idx] = run;
            cur[idx] = run;
            run += c[i];
        }
    }
    if (b == 0 && t == 0) off[Nn] = E;
}

__global__ void scatter_kernel(const int* __restrict__ src, const int* __restrict__ dst,
                               int E, int* __restrict__ cur, int* __restrict__ sorted) {
    int i = blockIdx.x * blockDim.x + threadIdx.x;
    if (i < E) {
        int d = dst[i];
        int p = atomicAdd(&cur[d], 1);
        sorted[p] = src[i];
    }
}

// ---------------- prep: f32->f16, W packing ----------------

__global__ void f32_to_f16(const float* __restrict__ in, _Float16* __restrict__ out, int n4) {
    int i = blockIdx.x * blockDim.x + threadIdx.x;
    if (i < n4) {
        float4 v = *reinterpret_cast<const float4*>(in + (size_t)i * 4);
        half4 h;
        h[0] = (_Float16)v.x; h[1] = (_Float16)v.y;
        h[2] = (_Float16)v.z; h[3] = (_Float16)v.w;
        *reinterpret_cast<half4*>(out + (size_t)i * 4) = h;
    }
}

// Wg granule p = (k/8)*N + n  holds f16 W[k..k+8][n] (8 k-values for column n).
__global__ void pack_w(const float* __restrict__ W, _Float16* __restrict__ Wg, int K, int N) {
    int p = blockIdx.x * blockDim.x + threadIdx.x;
    if (p < (K / 8) * N) {
        int j = p / N, n = p - j * N;
        half8 h;
#pragma unroll
        for (int i = 0; i < 8; ++i) h[i] = (_Float16)W[(size_t)(j * 8 + i) * N + n];
        *reinterpret_cast<half8*>(Wg + (size_t)p * 8) = h;
    }
}

// ---------------- fused GIN layer ----------------
// Block: 512 threads = 8 waves, 64 nodes (BM=64).
// Phase 1: gather + fp16 packed max + self-add -> LDS sA (swizzled granules).
//   granule p = j*64 + (row ^ (j&7)), j = k/8. Write: lanes spread over 8 bank-
//   quads (4-way). Read (16-lane group, j fixed): 2-way (free).
// Phase 2: per-wave 64xWN MFMA GEMM; A from LDS, B direct from L2-resident Wg.
// NG = edge streams per wave (64*8/K), NI = (N/8)/16 per-wave col tiles.

template <int K, int N, int NI, int NG, int OUT_F32, int RELU>
__global__ __launch_bounds__(512) void gin_layer(
    const _Float16* __restrict__ x, const int* __restrict__ off,
    const int* __restrict__ sorted, const _Float16* __restrict__ Wg,
    const float* __restrict__ bias, void* __restrict__ C, int Nn)
{
    __shared__ _Float16 sA[64 * K];

    const int tid  = threadIdx.x;
    const int wave = tid >> 6;
    const int lane = tid & 63;
    const int node0 = blockIdx.x * 64;

    // ---------- phase 1: aggregate 8 nodes per wave ----------
    constexpr int LPR = 64 / NG;       // lanes per row
    const int g   = lane / LPR;        // edge-stream id
    const int col = (lane % LPR) * 8;  // feature col (halves)
    const _Float16* xcol = x + col;

    for (int nd = 0; nd < 8; ++nd) {
        const int row = wave * 8 + nd;
        const int node = node0 + row;
        if (node >= Nn) break;         // uniform per wave
        const int beg = off[node];
        const int end = off[node + 1];

        half8 acc;
#pragma unroll
        for (int i = 0; i < 8; ++i) acc[i] = (_Float16)(-INFINITY);

        for (int eb = beg; eb < end; eb += 64) {
            const int cnt = min(64, end - eb);
            int myIdx = sorted[eb + (lane < cnt ? lane : cnt - 1)];
            const int nj = (cnt + NG - 1) / NG;
#pragma unroll 4
            for (int j = 0; j < nj; ++j) {
                int s = __shfl(myIdx, j * NG + g);
                half8 v = *reinterpret_cast<const half8*>(xcol + (size_t)s * K);
                acc = __builtin_elementwise_max(acc, v);
            }
        }

        union U { half8 h; int i[4]; };
        if (NG == 4) {
            U a, b; a.h = acc;
#pragma unroll
            for (int k = 0; k < 4; ++k) b.i[k] = __shfl_xor(a.i[k], 16);
            acc = __builtin_elementwise_max(a.h, b.h);
        }
        {
            U a, b; a.h = acc;
#pragma unroll
            for (int k = 0; k < 4; ++k) b.i[k] = __shfl_xor(a.i[k], 32);
            acc = __builtin_elementwise_max(a.h, b.h);
        }

        if (g == 0) {
            const bool hasEdges = (end > beg);
            half8 xv = *reinterpret_cast<const half8*>(xcol + (size_t)node * K);
            half8 o;
#pragma unroll
            for (int i = 0; i < 8; ++i)
                o[i] = (_Float16)((float)xv[i] + (hasEdges ? (float)acc[i] : 0.0f));
            const int j = lane;        // = col/8, lanes 0..K/8-1
            const int p = (j << 6) + (row ^ (j & 7));
            *reinterpret_cast<half8*>(&sA[p << 3]) = o;
        }
    }
    __syncthreads();

    // ---------- phase 2: C[64 x N] = sA[64 x K] @ W + bias ----------
    const int r  = lane & 15;
    const int gq = lane >> 4;          // k-subgroup 0..3
    const int nb = wave * (N / 8);     // wave's col base

    f32x4 acc2[4][NI];
#pragma unroll
    for (int mi = 0; mi < 4; ++mi)
#pragma unroll
        for (int ni = 0; ni < NI; ++ni) acc2[mi][ni] = (f32x4){0.f, 0.f, 0.f, 0.f};

    for (int k0 = 0; k0 < K; k0 += 32) {
        const int jb = (k0 >> 3) + gq;
        half8 aF[4];
#pragma unroll
        for (int mi = 0; mi < 4; ++mi) {
            int row = mi * 16 + r;
            int p = (jb << 6) + (row ^ (jb & 7));
            aF[mi] = *reinterpret_cast<const half8*>(&sA[p << 3]);
        }
        half8 bF[NI];
#pragma unroll
        for (int ni = 0; ni < NI; ++ni)
            bF[ni] = *reinterpret_cast<const half8*>(Wg + ((size_t)jb * N + nb + ni * 16 + r) * 8);
#pragma unroll
        for (int mi = 0; mi < 4; ++mi)
#pragma unroll
            for (int ni = 0; ni < NI; ++ni)
                acc2[mi][ni] = __builtin_amdgcn_mfma_f32_16x16x32_f16(aF[mi], bF[ni], acc2[mi][ni], 0, 0, 0);
    }

#pragma unroll
    for (int ni = 0; ni < NI; ++ni) {
        int colC = nb + ni * 16 + r;
        float bv = bias[colC];
#pragma unroll
        for (int mi = 0; mi < 4; ++mi) {
#pragma unroll
            for (int q = 0; q < 4; ++q) {
                int row = node0 + mi * 16 + (gq << 2) + q;
                if (row < Nn) {
                    float v = acc2[mi][ni][q] + bv;
                    if (RELU) v = fmaxf(v, 0.f);
                    if (OUT_F32) ((float*)C)[(size_t)row * N + colC] = v;
                    else         ((_Float16*)C)[(size_t)row * N + colC] = (_Float16)v;
                }
            }
        }
    }
}

// ---------------- launch ----------------

extern "C" void kernel_launch(void* const* d_in, const int* in_sizes, int n_in,
                              void* d_out, int out_size, void* d_ws, size_t ws_size,
                              hipStream_t stream) {
    const int*   src = (const int*)d_in[0];
    const int*   dst = (const int*)d_in[1];
    const float* emb = (const float*)d_in[2];
    const float* W1  = (const float*)d_in[3];
    const float* b1  = (const float*)d_in[4];
    const float* W2  = (const float*)d_in[5];
    const float* b2  = (const float*)d_in[6];
    const float* W3  = (const float*)d_in[7];
    const float* b3  = (const float*)d_in[8];
    float* out = (float*)d_out;

    const int E  = in_sizes[0];
    const int Nn = in_sizes[2] / EMB;

    char* ws = (char*)d_ws;
    auto align256 = [](size_t x) { return (x + 255) & ~(size_t)255; };
    size_t p = 0;
    int* off      = (int*)(ws + p); p = align256(p + (size_t)(Nn + 1) * 4);
    int* cur      = (int*)(ws + p); p = align256(p + (size_t)(Nn + 1) * 4);
    int* partials = (int*)(ws + p); p = align256(p + 256 * 4);
    int* sorted   = (int*)(ws + p); p = align256(p + (size_t)E * 4);
    _Float16* buf0 = (_Float16*)(ws + p); p = align256(p + (size_t)Nn * HIDN * 2);
    _Float16* buf1 = (_Float16*)(ws + p); p = align256(p + (size_t)Nn * HIDN * 2);
    _Float16* Wg1  = (_Float16*)(ws + p); p = align256(p + (size_t)EMB * HIDN * 2);
    _Float16* Wg2  = (_Float16*)(ws + p); p = align256(p + (size_t)HIDN * HIDN * 2);
    _Float16* Wg3  = (_Float16*)(ws + p); p = align256(p + (size_t)HIDN * EMB * 2);

    // ---- CSR build (by dst) ----
    const int nScanBlocks = (Nn + 1023) / 1024;
    zero_i32<<<(Nn + 255) / 256, 256, 0, stream>>>(cur, Nn);
    hist_kernel<<<(E + 255) / 256, 256, 0, stream>>>(dst, E, cur);
    scan_partial<<<nScanBlocks, 256, 0, stream>>>(cur, partials, Nn);
    scan_top<<<1, 256, 0, stream>>>(partials, nScanBlocks);
    scan_apply<<<nScanBlocks, 256, 0, stream>>>(cur, partials, off, cur, Nn, E);
    scatter_kernel<<<(E + 255) / 256, 256, 0, stream>>>(src, dst, E, cur, sorted);

    // ---- weight packing + emb -> fp16 ----
    pack_w<<<(EMB / 8 * HIDN + 255) / 256, 256, 0, stream>>>(W1, Wg1, EMB, HIDN);
    pack_w<<<(HIDN / 8 * HIDN + 255) / 256, 256, 0, stream>>>(W2, Wg2, HIDN, HIDN);
    pack_w<<<(HIDN / 8 * EMB + 255) / 256, 256, 0, stream>>>(W3, Wg3, HIDN, EMB);
    f32_to_f16<<<(Nn * EMB / 4 + 255) / 256, 256, 0, stream>>>(emb, buf0, Nn * EMB / 4);

    const int blocks = (Nn + 63) / 64;

    // Layer 1: K=128 -> N=256, relu
    gin_layer<128, 256, 2, 4, 0, 1><<<blocks, 512, 0, stream>>>(buf0, off, sorted, Wg1, b1, buf1, Nn);
    // Layer 2: K=256 -> N=256, relu
    gin_layer<256, 256, 2, 2, 0, 1><<<blocks, 512, 0, stream>>>(buf1, off, sorted, Wg2, b2, buf0, Nn);
    // Layer 3: K=256 -> N=128, no relu, f32 out
    gin_layer<256, 128, 1, 2, 1, 0><<<blocks, 512, 0, stream>>>(buf0, off, sorted, Wg3, b3, out, Nn);
}